// Round 18
// baseline (229.415 us; speedup 1.0000x reference)
//
#include <hip/hip_runtime.h>

#define KK  128   // samples per ray
#define RPW 8     // rays per wave (wave-private)
#define TPB 128   // 2 independent waves per block; 8 KB LDS/block

// borders = [z0, 0.5f*(z[i]+z[i-1]), z127]; expression text identical to R8-R17
__device__ __forceinline__ float blerp(const float* __restrict__ Z, int c, float t)
{
    float zc = Z[c];
    float zm = Z[c > 0 ? c - 1 : 0];
    float zp = Z[c < KK - 1 ? c + 1 : KK - 1];
    float left  = (c == 0)      ? zc : 0.5f * (zc + zm);
    float right = (c == KK - 1) ? zc : 0.5f * (zp + zc);
    return left * (1.0f - t) + right * t;
}

__global__ __launch_bounds__(TPB, 8)   // R17 body fits in 40 VGPR -> safe at cap 64
void nerf_sample_kernel(const float* __restrict__ Wg,
                        const float* __restrict__ Zg,
                        const float* __restrict__ Ug,
                        const float* __restrict__ Tg,
                        float* __restrict__ Og)
{
    // wave-private 4KB cdf region; NO __syncthreads (single-wave DS ordering)
    __shared__ float S[2 * RPW * KK];   // 8 KB/block
    const int lane = threadIdx.x & 63;
    const int wvid = threadIdx.x >> 6;
    float* SW = S + wvid * (RPW * KK);

    const int r   = lane >> 3;          // build: ray slot 0..7
    const int h   = lane & 7;           // build: owns elements [16h, 16h+16)
    const int swz = r << 3;             // 8-float-block XOR swizzle across rows
    float* Srow = SW + r * KK;

    const size_t grp   = (size_t)blockIdx.x * 2 + wvid;
    const size_t gbase = grp * (RPW * KK);
    const size_t rbase = gbase + (size_t)r * KK;

    // ---- prefetch u/t tiles 0,1 (4 x 1KB wave-linear), in flight during build ----
    float4 ua = *(const float4*)(Ug + gbase +   0 + 4 * lane);
    float4 ta = *(const float4*)(Tg + gbase +   0 + 4 * lane);
    float4 ub = *(const float4*)(Ug + gbase + 256 + 4 * lane);
    float4 tb = *(const float4*)(Tg + gbase + 256 + 4 * lane);

    // ---- load own 16 weights; w' = fl32(w + 1e-5f) ----
    float x[16];
    {
        const float* wp = Wg + rbase + 16 * h;
        #pragma unroll
        for (int e = 0; e < 4; ++e) {
            float4 v = *(const float4*)(wp + 4 * e);
            x[4*e+0] = v.x + 1e-5f;
            x[4*e+1] = v.y + 1e-5f;
            x[4*e+2] = v.z + 1e-5f;
            x[4*e+3] = v.w + 1e-5f;
        }
    }

    // ---- tot: npyv model, EXACT R8 grouping (verbatim) ----
    float tot;
    {
        float Cc[16];
        #pragma unroll
        for (int c = 0; c < 16; ++c) {
            float a = x[c] + __shfl_xor(x[c], 4);
            float b = a    + __shfl_xor(a, 1);
            Cc[c]   = b    + __shfl_xor(b, 2);
        }
        float Uu[8];
        #pragma unroll
        for (int c = 0; c < 8; ++c) Uu[c] = Cc[c] + Cc[c + 8];
        float Vv[4];
        #pragma unroll
        for (int c = 0; c < 4; ++c) Vv[c] = Uu[c] + Uu[c + 4];
        tot = (Vv[0] + Vv[2]) + (Vv[1] + Vv[3]);
    }

    // ---- pdf: IEEE f32 divide ----
    #pragma unroll
    for (int j = 0; j < 16; ++j) x[j] = x[j] / tot;

    // ---- BK scan levels 1-4 lane-local (verbatim) ----
    #pragma unroll
    for (int m = 0; m < 8; ++m) x[2*m+1] = x[2*m+1] + x[2*m];
    #pragma unroll
    for (int m = 0; m < 4; ++m) x[4*m+3] = x[4*m+3] + x[4*m+1];
    #pragma unroll
    for (int m = 0; m < 2; ++m) x[8*m+7] = x[8*m+7] + x[8*m+3];
    x[15] = x[15] + x[7];

    // ---- cross-lane levels + prefix P (verbatim) ----
    {
        float s    = x[15];
        float sx1  = __shfl_xor(s, 1);
        float t1   = s + sx1;
        float t1x2 = __shfl_xor(t1, 2);
        float t2   = t1 + t1x2;
        float t2x4 = __shfl_xor(t2, 4);
        float c95  = t1x2 + t2x4;

        float xf =
            (h == 0) ? s :
            (h == 1) ? t1 :
            (h == 2) ? s + t1x2 :
            (h == 3) ? t2 :
            (h == 4) ? s + t2x4 :
            (h == 5) ? t1 + t2x4 :
            (h == 6) ? s + c95 :
                       t2 + t2x4;
        x[15] = xf;

        float P =
            (h == 0) ? 0.0f :
            (h == 1) ? sx1 :
            (h == 2) ? t1x2 :
            (h == 3) ? sx1 + t1x2 :
            (h == 4) ? t2x4 :
            (h == 5) ? sx1 + t2x4 :
            (h == 6) ? c95 :
                       sx1 + c95;

        x[7]  = x[7]  + P;
        x[3]  = x[3]  + P;  x[11] = x[11] + x[7];
        x[1]  = x[1]  + P;  x[5]  = x[5]  + x[3];
        x[9]  = x[9]  + x[7];  x[13] = x[13] + x[11];
        x[0]  = x[0]  + P;
        #pragma unroll
        for (int m = 1; m < 8; ++m) x[2*m] = x[2*m] + x[2*m-1];
    }

    // ---- write cdf to wave-private LDS (swizzled) ----
    #pragma unroll
    for (int e = 0; e < 4; ++e)
        *(float4*)(Srow + ((16*h + 4*e) ^ swz)) =
            make_float4(x[4*e+0], x[4*e+1], x[4*e+2], x[4*e+3]);

    // wave-level fence: stop compiler moving search reads above the writes
    __builtin_amdgcn_sched_barrier(0);
    __builtin_amdgcn_wave_barrier();
    __builtin_amdgcn_sched_barrier(0);

    // ---- phase C: 2 super-iterations; 8 concurrent binary chains per lane
    // (two rays' tiles at once). I/O stays 1KB wave-linear. Prefetch depth 2.
    const float EPSL = 1.0f - 1.8e-7f;
    const float EPSH = 1.0f + 1.8e-7f;
    const int rhalf = lane >> 5;

    #pragma unroll
    for (int sit = 0; sit < 2; ++sit) {
        const int ita = 2 * sit, itb = 2 * sit + 1;
        const int ra  = 2 * ita + rhalf;        // ray for chains 0..3
        const int rb  = 2 * itb + rhalf;        // ray for chains 4..7

        float4 cua = ua, cta = ta, cub = ub, ctb = tb;
        if (sit == 0) {   // prefetch tiles 2,3 during super-iteration 0
            ua = *(const float4*)(Ug + gbase + 512 + 4 * lane);
            ta = *(const float4*)(Tg + gbase + 512 + 4 * lane);
            ub = *(const float4*)(Ug + gbase + 768 + 4 * lane);
            tb = *(const float4*)(Tg + gbase + 768 + 4 * lane);
        }

        const float* ca = SW + ra * KK;  const int cswa = ra << 3;
        const float* cb = SW + rb * KK;  const int cswb = rb << 3;

        float uu[8] = {cua.x, cua.y, cua.z, cua.w, cub.x, cub.y, cub.z, cub.w};
        float tv[8] = {cta.x, cta.y, cta.z, cta.w, ctb.x, ctb.y, ctb.z, ctb.w};
        float ul[8], uh[8];
        int hh[8];
        #pragma unroll
        for (int i = 0; i < 8; ++i) {
            ul[i] = uu[i] * EPSL;
            uh[i] = uu[i] * EPSH;
            hh[i] = 0;
        }
        #pragma unroll
        for (int s = 64; s >= 1; s >>= 1) {   // 8 interleaved binary chains
            #pragma unroll
            for (int i = 0; i < 8; ++i) {
                const float* crow = (i < 4) ? ca : cb;
                const int    csw  = (i < 4) ? cswa : cswb;
                float b = crow[(hh[i] + s - 1) ^ csw];
                if (b <= uh[i]) hh[i] += s;
            }
        }

        const float* Za = Zg + gbase + (size_t)ra * KK;
        const float* Zb = Zg + gbase + (size_t)rb * KK;
        float res[8];
        #pragma unroll
        for (int i = 0; i < 8; ++i) {
            const float* crow = (i < 4) ? ca : cb;
            const int    csw  = (i < 4) ? cswa : cswb;
            const float* Z    = (i < 4) ? Za : Zb;
            const int hi = hh[i];                 // #{cdf<=uh} capped at 127
            int li = hi;                          // l differs only in hedge window
            while (li > 0 && crow[(li - 1) ^ csw] > ul[i]) --li;
            res[i] = (li == hi) ? blerp(Z, hi, tv[i])
                                : 0.5f * (blerp(Z, li, tv[i]) + blerp(Z, hi, tv[i]));
        }
        *(float4*)(Og + gbase + ita * 256 + 4 * lane) =
            make_float4(res[0], res[1], res[2], res[3]);
        *(float4*)(Og + gbase + itb * 256 + 4 * lane) =
            make_float4(res[4], res[5], res[6], res[7]);
    }
}

extern "C" void kernel_launch(void* const* d_in, const int* in_sizes, int n_in,
                              void* d_out, int out_size, void* d_ws, size_t ws_size,
                              hipStream_t stream)
{
    // inputs: 0=rays (unused), 1=weights, 2=z_samp, 3=u, 4=interval_interp
    const float* Wg = (const float*)d_in[1];
    const float* Zg = (const float*)d_in[2];
    const float* Ug = (const float*)d_in[3];
    const float* Tg = (const float*)d_in[4];
    float* Og = (float*)d_out;

    const int nrays  = in_sizes[1] / KK;        // 262144
    const int blocks = nrays / (2 * RPW);       // 16384 (2 waves x 8 rays)

    nerf_sample_kernel<<<dim3(blocks), dim3(TPB), 0, stream>>>(Wg, Zg, Ug, Tg, Og);
}

// Round 19
// 130.557 us; speedup vs baseline: 1.7572x; 1.7572x over previous
//
#include <hip/hip_runtime.h>

#define KK  128   // samples per ray
#define RPW 8     // rays per wave (wave-private)
#define TPB 128   // 2 independent waves per block
// per-wave LDS: 8x128 cdf + 8x132 borders = 2080 floats (8320 B)

__global__ __launch_bounds__(TPB, 6)   // cap 85 VGPR (R17-class body ~40-60, no spill)
void nerf_sample_kernel(const float* __restrict__ Wg,
                        const float* __restrict__ Zg,
                        const float* __restrict__ Ug,
                        const float* __restrict__ Tg,
                        float* __restrict__ Og)
{
    __shared__ float S[2 * 2080];       // 16.6 KB/block
    const int lane = threadIdx.x & 63;
    const int wvid = threadIdx.x >> 6;
    float* CW = S + wvid * 2080;        // cdf rows: 8 x 128 (XOR-swizzled)
    float* BW = CW + 1024;              // border rows: 8 x 132 (linear)

    const int r   = lane >> 3;          // build: ray slot 0..7
    const int h   = lane & 7;           // build: owns elements [16h, 16h+16)
    const int swz = r << 3;             // 8-float-block XOR swizzle (cdf rows)
    float* Srow = CW + r * KK;
    float* Brow = BW + r * 132;

    const size_t grp   = (size_t)blockIdx.x * 2 + wvid;
    const size_t gbase = grp * (RPW * KK);
    const size_t rbase = gbase + (size_t)r * KK;

    // ---- phase-C it=0 prefetch: wave-linear 1KB loads ----
    float4 cu = *(const float4*)(Ug + gbase + 4 * lane);
    float4 ct = *(const float4*)(Tg + gbase + 4 * lane);

    // ---- load own 16 weights (coalesced); w' = fl32(w + 1e-5f) ----
    float x[16];
    {
        const float* wp = Wg + rbase + 16 * h;
        #pragma unroll
        for (int e = 0; e < 4; ++e) {
            float4 v = *(const float4*)(wp + 4 * e);
            x[4*e+0] = v.x + 1e-5f;
            x[4*e+1] = v.y + 1e-5f;
            x[4*e+2] = v.z + 1e-5f;
            x[4*e+3] = v.w + 1e-5f;
        }
    }

    // ---- load own 16 z values (coalesced) — in flight during tot/scan ----
    float zr[16];
    {
        const float* zp = Zg + rbase + 16 * h;
        #pragma unroll
        for (int e = 0; e < 4; ++e) {
            float4 v = *(const float4*)(zp + 4 * e);
            zr[4*e+0] = v.x; zr[4*e+1] = v.y; zr[4*e+2] = v.z; zr[4*e+3] = v.w;
        }
    }

    // ---- tot: npyv model, EXACT R8 grouping (verbatim) ----
    float tot;
    {
        float Cc[16];
        #pragma unroll
        for (int c = 0; c < 16; ++c) {
            float a = x[c] + __shfl_xor(x[c], 4);
            float b = a    + __shfl_xor(a, 1);
            Cc[c]   = b    + __shfl_xor(b, 2);
        }
        float Uu[8];
        #pragma unroll
        for (int c = 0; c < 8; ++c) Uu[c] = Cc[c] + Cc[c + 8];
        float Vv[4];
        #pragma unroll
        for (int c = 0; c < 4; ++c) Vv[c] = Uu[c] + Uu[c + 4];
        tot = (Vv[0] + Vv[2]) + (Vv[1] + Vv[3]);
    }

    // ---- pdf: IEEE f32 divide ----
    #pragma unroll
    for (int j = 0; j < 16; ++j) x[j] = x[j] / tot;

    // ---- BK scan levels 1-4 lane-local (verbatim) ----
    #pragma unroll
    for (int m = 0; m < 8; ++m) x[2*m+1] = x[2*m+1] + x[2*m];
    #pragma unroll
    for (int m = 0; m < 4; ++m) x[4*m+3] = x[4*m+3] + x[4*m+1];
    #pragma unroll
    for (int m = 0; m < 2; ++m) x[8*m+7] = x[8*m+7] + x[8*m+3];
    x[15] = x[15] + x[7];

    // ---- cross-lane levels + prefix P (verbatim) ----
    {
        float s    = x[15];
        float sx1  = __shfl_xor(s, 1);
        float t1   = s + sx1;
        float t1x2 = __shfl_xor(t1, 2);
        float t2   = t1 + t1x2;
        float t2x4 = __shfl_xor(t2, 4);
        float c95  = t1x2 + t2x4;

        float xf =
            (h == 0) ? s :
            (h == 1) ? t1 :
            (h == 2) ? s + t1x2 :
            (h == 3) ? t2 :
            (h == 4) ? s + t2x4 :
            (h == 5) ? t1 + t2x4 :
            (h == 6) ? s + c95 :
                       t2 + t2x4;
        x[15] = xf;

        float P =
            (h == 0) ? 0.0f :
            (h == 1) ? sx1 :
            (h == 2) ? t1x2 :
            (h == 3) ? sx1 + t1x2 :
            (h == 4) ? t2x4 :
            (h == 5) ? sx1 + t2x4 :
            (h == 6) ? c95 :
                       sx1 + c95;

        x[7]  = x[7]  + P;
        x[3]  = x[3]  + P;  x[11] = x[11] + x[7];
        x[1]  = x[1]  + P;  x[5]  = x[5]  + x[3];
        x[9]  = x[9]  + x[7];  x[13] = x[13] + x[11];
        x[0]  = x[0]  + P;
        #pragma unroll
        for (int m = 1; m < 8; ++m) x[2*m] = x[2*m] + x[2*m-1];
    }

    // ---- write cdf to wave-private LDS (swizzled) ----
    #pragma unroll
    for (int e = 0; e < 4; ++e)
        *(float4*)(Srow + ((16*h + 4*e) ^ swz)) =
            make_float4(x[4*e+0], x[4*e+1], x[4*e+2], x[4*e+3]);

    // ---- borders: B[0]=z0; B[j]=0.5f*(z[j]+z[j-1]); B[128]=z127.
    // Identical expressions/operand order to the old blerp -> values bit-equal.
    {
        float zprev = __shfl_up(zr[15], 1);   // z[16h-1] (garbage for h==0, unused)
        float B[16];
        B[0] = (h == 0) ? zr[0] : 0.5f * (zr[0] + zprev);
        #pragma unroll
        for (int k = 1; k < 16; ++k) B[k] = 0.5f * (zr[k] + zr[k-1]);
        #pragma unroll
        for (int e = 0; e < 4; ++e)
            *(float4*)(Brow + 16*h + 4*e) =
                make_float4(B[4*e+0], B[4*e+1], B[4*e+2], B[4*e+3]);
        if (h == 7) Brow[128] = zr[15];
    }

    // wave-level fence: stop compiler moving search reads above the writes
    __builtin_amdgcn_sched_barrier(0);
    __builtin_amdgcn_wave_barrier();
    __builtin_amdgcn_sched_barrier(0);

    // ---- phase C (R14 structure): it serves rays {2it,2it+1}; lane = flat 4*lane.
    // ALL reads are LDS now (no scattered VMEM -> TA pipe freed).
    const float EPSL = 1.0f - 1.8e-7f;
    const float EPSH = 1.0f + 1.8e-7f;
    const int rhalf = lane >> 5;

    for (int it = 0; it < 4; ++it) {
        float4 uu4 = cu, tt4 = ct;
        if (it < 3) {
            cu = *(const float4*)(Ug + gbase + (it + 1) * 256 + 4 * lane);
            ct = *(const float4*)(Tg + gbase + (it + 1) * 256 + 4 * lane);
        }

        const int rr = 2 * it + rhalf;
        const float* crow = CW + rr * KK;
        const float* brow = BW + rr * 132;
        const int csw = rr << 3;

        float uu[4] = {uu4.x, uu4.y, uu4.z, uu4.w};
        float tv[4] = {tt4.x, tt4.y, tt4.z, tt4.w};
        float ul[4], uh[4];
        int hh[4];
        #pragma unroll
        for (int i = 0; i < 4; ++i) {
            ul[i] = uu[i] * EPSL;
            uh[i] = uu[i] * EPSH;
            hh[i] = 0;
        }
        #pragma unroll
        for (int s = 64; s >= 1; s >>= 1) {   // 4 independent binary chains
            #pragma unroll
            for (int i = 0; i < 4; ++i) {
                float b = crow[(hh[i] + s - 1) ^ csw];
                if (b <= uh[i]) hh[i] += s;
            }
        }

        float res[4];
        #pragma unroll
        for (int i = 0; i < 4; ++i) {
            const int hi = hh[i];                 // #{cdf<=uh}, structurally <=127
            int li = hi;                          // l differs only in hedge window
            while (li > 0 && crow[(li - 1) ^ csw] > ul[i]) --li;
            float lb = brow[hi], rb = brow[hi + 1];
            float r1 = lb * (1.0f - tv[i]) + rb * tv[i];
            if (li != hi) {
                float lb2 = brow[li], rb2 = brow[li + 1];
                float r0 = lb2 * (1.0f - tv[i]) + rb2 * tv[i];
                r1 = 0.5f * (r0 + r1);
            }
            res[i] = r1;
        }
        *(float4*)(Og + gbase + it * 256 + 4 * lane) =
            make_float4(res[0], res[1], res[2], res[3]);
    }
}

extern "C" void kernel_launch(void* const* d_in, const int* in_sizes, int n_in,
                              void* d_out, int out_size, void* d_ws, size_t ws_size,
                              hipStream_t stream)
{
    // inputs: 0=rays (unused), 1=weights, 2=z_samp, 3=u, 4=interval_interp
    const float* Wg = (const float*)d_in[1];
    const float* Zg = (const float*)d_in[2];
    const float* Ug = (const float*)d_in[3];
    const float* Tg = (const float*)d_in[4];
    float* Og = (float*)d_out;

    const int nrays  = in_sizes[1] / KK;        // 262144
    const int blocks = nrays / (2 * RPW);       // 16384 (2 waves x 8 rays)

    nerf_sample_kernel<<<dim3(blocks), dim3(TPB), 0, stream>>>(Wg, Zg, Ug, Tg, Og);
}

// Round 20
// 128.478 us; speedup vs baseline: 1.7856x; 1.0162x over previous
//
#include <hip/hip_runtime.h>

#define KK  128   // samples per ray
#define RPW 4     // rays per wave (wave-private); 16 lanes per ray in build
#define TPB 128   // 2 independent waves per block; 8.3 KB LDS/block

__global__ __launch_bounds__(TPB, 8)
void nerf_sample_kernel(const float* __restrict__ Wg,
                        const float* __restrict__ Zg,
                        const float* __restrict__ Ug,
                        const float* __restrict__ Tg,
                        float* __restrict__ Og)
{
    // per-wave: 4x128 cdf (swizzled) + 4x132 borders = 1040 floats (4160 B)
    __shared__ float S[2 * 1040];
    const int lane = threadIdx.x & 63;
    const int wvid = threadIdx.x >> 6;
    float* CW = S + wvid * 1040;        // cdf rows
    float* BW = CW + 512;               // border rows (stride 132)

    const int r   = lane >> 4;          // build: ray slot 0..3
    const int h   = lane & 15;          // build: owns elements [8h, 8h+8)
    const int swz = r << 3;             // 8-float-block XOR swizzle (cdf rows)
    float* Srow = CW + r * KK;
    float* Brow = BW + r * 132;

    const size_t grp   = (size_t)blockIdx.x * 2 + wvid;
    const size_t gbase = grp * (RPW * KK);
    const size_t rbase = gbase + (size_t)r * KK;

    // ---- phase-C it=0 prefetch: wave-linear 1KB loads ----
    float4 cu = *(const float4*)(Ug + gbase + 4 * lane);
    float4 ct = *(const float4*)(Tg + gbase + 4 * lane);

    // ---- load own 8 weights; w' = fl32(w + 1e-5f) ----
    float x[8];
    {
        const float* wp = Wg + rbase + 8 * h;
        #pragma unroll
        for (int e = 0; e < 2; ++e) {
            float4 v = *(const float4*)(wp + 4 * e);
            x[4*e+0] = v.x + 1e-5f;
            x[4*e+1] = v.y + 1e-5f;
            x[4*e+2] = v.z + 1e-5f;
            x[4*e+3] = v.w + 1e-5f;
        }
    }

    // ---- load own 8 z values (in flight during tot/scan) ----
    float zr[8];
    {
        const float* zp = Zg + rbase + 8 * h;
        float4 v0 = *(const float4*)(zp);
        float4 v1 = *(const float4*)(zp + 4);
        zr[0]=v0.x; zr[1]=v0.y; zr[2]=v0.z; zr[3]=v0.w;
        zr[4]=v1.x; zr[5]=v1.y; zr[6]=v1.z; zr[7]=v1.w;
    }

    // ---- tot: npyv model, EXACT R8 grouping. Chunk k=h>>1 lives on lanes
    // {2k,2k+1}; position p=(h&1)*8+j. a=V_k+V_{k+4} (xor8); pairs (xor2);
    // outer (xor4); U=Sv[c]+Sv[c+8] (xor1); V4/tot intra-lane. All swapped
    // operands are single commutative adds -> bitwise identical.
    float tot;
    {
        float Cc[8];
        #pragma unroll
        for (int j = 0; j < 8; ++j) {
            float a = x[j] + __shfl_xor(x[j], 8);
            float b = a    + __shfl_xor(a, 2);
            float c = b    + __shfl_xor(b, 4);
            Cc[j]   = c    + __shfl_xor(c, 1);      // U[j]
        }
        float V0 = Cc[0] + Cc[4];
        float V1 = Cc[1] + Cc[5];
        float V2 = Cc[2] + Cc[6];
        float V3 = Cc[3] + Cc[7];
        tot = (V0 + V2) + (V1 + V3);
    }

    // ---- pdf: IEEE f32 divide ----
    #pragma unroll
    for (int j = 0; j < 8; ++j) x[j] = x[j] / tot;

    // ---- BK scan: levels 1-3 lane-local (8 elements) ----
    x[1] = x[1] + x[0];  x[3] = x[3] + x[2];
    x[5] = x[5] + x[4];  x[7] = x[7] + x[6];
    x[3] = x[3] + x[1];  x[7] = x[7] + x[5];
    x[7] = x[7] + x[3];

    // ---- segment-space BK over 16 lanes: C_h (final cdf at 8h+7) and
    // P_h = C_{h-1}; groupings verified against global BK levels 4-7.
    {
        float s     = x[7];
        float sx1   = __shfl_xor(s, 1);
        float pair  = s + sx1;
        float pairx2 = __shfl_xor(pair, 2);
        float quad  = pair + pairx2;
        float quadx4 = __shfl_xor(quad, 4);
        float oct   = quad + quadx4;
        float octx8 = __shfl_xor(oct, 8);

        // P = [sx1 +] ([pairx2 +] ([quadx4 +] [octx8])), right-assoc by bits of h
        float tP = (h & 8) ? octx8 : 0.0f;
        tP = (h & 4) ? (quadx4 + tP) : tP;
        tP = (h & 2) ? (pairx2 + tP) : tP;
        float P = (h & 1) ? (sx1 + tP) : tP;        // exact: +0.0f is exact, all >0

        // C_h: from the BK up/down tree structure
        float c5v  = pairx2 + quadx4;                // C5 seen from lane 6
        float c9v  = pairx2 + octx8;                 // C9 seen from lane 10
        float c11v = quadx4 + octx8;                 // C11 seen from lanes 12,13
        float c13v = pairx2 + c11v;                  // C13 seen from lane 14
        float C =
            (h ==  0) ? s :
            (h ==  1) ? pair :
            (h ==  2) ? s + pairx2 :
            (h ==  3) ? quad :
            (h ==  4) ? s + quadx4 :
            (h ==  5) ? pair + quadx4 :
            (h ==  6) ? s + c5v :
            (h ==  7) ? oct :
            (h ==  8) ? s + octx8 :
            (h ==  9) ? pair + octx8 :
            (h == 10) ? s + c9v :
            (h == 11) ? quad + octx8 :
            (h == 12) ? s + c11v :
            (h == 13) ? pair + c11v :
            (h == 14) ? s + c13v :
                        oct + octx8;
        x[7] = C;

        // local down-sweep with P injected (global levels 3,2,1)
        x[3] = x[3] + P;
        x[1] = x[1] + P;  x[5] = x[5] + x[3];
        x[0] = x[0] + P;  x[2] = x[2] + x[1];
        x[4] = x[4] + x[3];  x[6] = x[6] + x[5];
    }

    // ---- write cdf to wave-private LDS (8-float-block XOR swizzle) ----
    *(float4*)(Srow + ((8*h    ) ^ swz)) = make_float4(x[0], x[1], x[2], x[3]);
    *(float4*)(Srow + ((8*h + 4) ^ swz)) = make_float4(x[4], x[5], x[6], x[7]);

    // ---- borders: B[0]=z0; B[j]=0.5f*(z[j]+z[j-1]); B[128]=z127 ----
    {
        float zprev = __shfl_up(zr[7], 1);   // z[8h-1] (unused when h==0)
        float B0 = (h == 0) ? zr[0] : 0.5f * (zr[0] + zprev);
        float B1 = 0.5f * (zr[1] + zr[0]);
        float B2 = 0.5f * (zr[2] + zr[1]);
        float B3 = 0.5f * (zr[3] + zr[2]);
        float B4 = 0.5f * (zr[4] + zr[3]);
        float B5 = 0.5f * (zr[5] + zr[4]);
        float B6 = 0.5f * (zr[6] + zr[5]);
        float B7 = 0.5f * (zr[7] + zr[6]);
        *(float4*)(Brow + 8*h    ) = make_float4(B0, B1, B2, B3);
        *(float4*)(Brow + 8*h + 4) = make_float4(B4, B5, B6, B7);
        if (h == 15) Brow[128] = zr[7];
    }

    // wave-level fence: stop compiler moving search reads above the writes
    __builtin_amdgcn_sched_barrier(0);
    __builtin_amdgcn_wave_barrier();
    __builtin_amdgcn_sched_barrier(0);

    // ---- phase C: 2 iterations; it serves rays {2it, 2it+1}; lane = flat 4*lane.
    // All reads LDS; I/O 1KB wave-linear.
    const float EPSL = 1.0f - 1.8e-7f;
    const float EPSH = 1.0f + 1.8e-7f;
    const int rhalf = lane >> 5;

    #pragma unroll
    for (int it = 0; it < 2; ++it) {
        float4 uu4 = cu, tt4 = ct;
        if (it == 0) {
            cu = *(const float4*)(Ug + gbase + 256 + 4 * lane);
            ct = *(const float4*)(Tg + gbase + 256 + 4 * lane);
        }

        const int rr = 2 * it + rhalf;
        const float* crow = CW + rr * KK;
        const float* brow = BW + rr * 132;
        const int csw = rr << 3;

        float uu[4] = {uu4.x, uu4.y, uu4.z, uu4.w};
        float tv[4] = {tt4.x, tt4.y, tt4.z, tt4.w};
        float ul[4], uh[4];
        int hh[4];
        #pragma unroll
        for (int i = 0; i < 4; ++i) {
            ul[i] = uu[i] * EPSL;
            uh[i] = uu[i] * EPSH;
            hh[i] = 0;
        }
        #pragma unroll
        for (int s = 64; s >= 1; s >>= 1) {   // 4 independent binary chains
            #pragma unroll
            for (int i = 0; i < 4; ++i) {
                float b = crow[(hh[i] + s - 1) ^ csw];
                if (b <= uh[i]) hh[i] += s;
            }
        }

        float res[4];
        #pragma unroll
        for (int i = 0; i < 4; ++i) {
            const int hi = hh[i];                 // #{cdf<=uh}, structurally <=127
            int li = hi;                          // l differs only in hedge window
            while (li > 0 && crow[(li - 1) ^ csw] > ul[i]) --li;
            float lb = brow[hi], rb = brow[hi + 1];
            float r1 = lb * (1.0f - tv[i]) + rb * tv[i];
            if (li != hi) {
                float lb2 = brow[li], rb2 = brow[li + 1];
                float r0 = lb2 * (1.0f - tv[i]) + rb2 * tv[i];
                r1 = 0.5f * (r0 + r1);
            }
            res[i] = r1;
        }
        *(float4*)(Og + gbase + it * 256 + 4 * lane) =
            make_float4(res[0], res[1], res[2], res[3]);
    }
}

extern "C" void kernel_launch(void* const* d_in, const int* in_sizes, int n_in,
                              void* d_out, int out_size, void* d_ws, size_t ws_size,
                              hipStream_t stream)
{
    // inputs: 0=rays (unused), 1=weights, 2=z_samp, 3=u, 4=interval_interp
    const float* Wg = (const float*)d_in[1];
    const float* Zg = (const float*)d_in[2];
    const float* Ug = (const float*)d_in[3];
    const float* Tg = (const float*)d_in[4];
    float* Og = (float*)d_out;

    const int nrays  = in_sizes[1] / KK;        // 262144
    const int blocks = nrays / (2 * RPW);       // 32768 (2 waves x 4 rays)

    nerf_sample_kernel<<<dim3(blocks), dim3(TPB), 0, stream>>>(Wg, Zg, Ug, Tg, Og);
}